// Round 17
// baseline (2674.641 us; speedup 1.0000x reference)
//
#include <hip/hip_runtime.h>
#include <hip/hip_bf16.h>

#define TL 2048
#define NB 64
#define NH 64
#define NLAY 10
#define NRESU 3
#define RSTEP 64

typedef float f32x4 __attribute__((ext_vector_type(4)));
typedef short bhalf8 __attribute__((ext_vector_type(8)));
typedef short bhalf4 __attribute__((ext_vector_type(4)));

__device__ __forceinline__ unsigned short f2bf(float f) {
    unsigned u = __float_as_uint(f);
    unsigned r = u + 0x7fffu + ((u >> 16) & 1u);
    return (unsigned short)(r >> 16);
}
__device__ __forceinline__ float bf2f(unsigned short h) {
    return __uint_as_float(((unsigned)h) << 16);
}
// raw 2^x / 2^-x (v_exp_f32; neg is a free input modifier)
__device__ __forceinline__ float exp2_pos(float x) {
    float r; asm("v_exp_f32 %0, %1" : "=v"(r) : "v"(x)); return r;
}
__device__ __forceinline__ float exp2_neg(float x) {
    float r; asm("v_exp_f32 %0, -%1" : "=v"(r) : "v"(x)); return r;
}

// ---------------- frontend ----------------
__global__ __launch_bounds__(256) void k_frontend(
    const float* __restrict__ in,
    const float* __restrict__ c1w, const float* __restrict__ c1b,
    const float* __restrict__ c2w, const float* __restrict__ c2b,
    float* __restrict__ x0)
{
    __shared__ float s_c1w[128];
    __shared__ float s_c1b[32];
    __shared__ float s_c2w[64 * 33];
    __shared__ float s_c2b[64];
    __shared__ float h1[64 * 33];
    __shared__ float ot[64 * 65];
    int tid = threadIdx.x;
    int b = blockIdx.x >> 5;
    int l0 = (blockIdx.x & 31) << 6;
    if (tid < 128) s_c1w[tid] = c1w[tid];
    if (tid < 32) s_c1b[tid] = c1b[tid];
    if (tid < 64) s_c2b[tid] = c2b[tid];
    for (int r = tid; r < 2048; r += 256) s_c2w[(r >> 5) * 33 + (r & 31)] = c2w[r];
    __syncthreads();
    if (tid < 64) {
        const float* ip = in + ((size_t)b * TL + l0 + tid) * 4;
        float x0v = ip[0], x1 = ip[1], x2 = ip[2], x3 = ip[3];
#pragma unroll
        for (int o = 0; o < 32; o++) {
            float a = s_c1w[o * 4 + 0] * x0v + s_c1w[o * 4 + 1] * x1 +
                      s_c1w[o * 4 + 2] * x2 + s_c1w[o * 4 + 3] * x3 + s_c1b[o];
            h1[tid * 33 + o] = fmaxf(a, 0.0f);
        }
    }
    __syncthreads();
    {
        int o = tid & 63, lg = tid >> 6;
#pragma unroll
        for (int j = 0; j < 16; j++) {
            int l = lg * 16 + j;
            float a = s_c2b[o];
#pragma unroll
            for (int i = 0; i < 32; i++) a += h1[l * 33 + i] * s_c2w[o * 33 + i];
            ot[o * 65 + l] = fmaxf(a, 0.0f);
        }
    }
    __syncthreads();
    for (int r = 0; r < 16; r++) {
        int idx = tid + 256 * r;
        int c = idx >> 6, l = idx & 63;
        x0[((size_t)b * 64 + c) * TL + l0 + l] = ot[c * 65 + l];
    }
}

// ---------------- weight prep: [u][o][i][k] f32 -> [u][k][o][i] bf16 hi/lo ----------------
__global__ __launch_bounds__(256) void k_prepw_mfma(
    const float* __restrict__ w, unsigned short* __restrict__ wbh, unsigned short* __restrict__ wbl)
{
    int idx = blockIdx.x * 256 + threadIdx.x;
    if (idx >= NRESU * 11 * 64 * 64) return;
    int i = idx & 63;
    int rest = idx >> 6;
    int o = rest & 63;
    rest >>= 6;
    int k = rest % 11;
    int u = rest / 11;
    float v = w[(((size_t)u * 64 + o) * 64 + i) * 11 + k];
    unsigned short hb = f2bf(v);
    float lo = v - bf2f(hb);
    wbh[idx] = hb;
    wbl[idx] = f2bf(lo);
}

// ---------------- residual conv k=11 pad=5 via MFMA (3-term split bf16) ----------------
#define XTS 76
__global__ __launch_bounds__(256) void k_resconv_mfma(
    const float* __restrict__ in, float* __restrict__ out,
    const unsigned short* __restrict__ wbh, const unsigned short* __restrict__ wbl,
    const float* __restrict__ bias,
    const float* __restrict__ bg, const float* __restrict__ bb,
    const float* __restrict__ bm, const float* __restrict__ bv,
    int accumulate)
{
    __shared__ float sscale[64], sshift[64];
    __shared__ __align__(16) char smem[43776];
    unsigned short* XTH = (unsigned short*)smem;           // [144][76]
    unsigned short* XTL = XTH + 144 * XTS;                 // [144][76]
    float* Yb = (float*)smem;                              // [128][66] overlay (post-MFMA)

    int tid = threadIdx.x;
    int b = blockIdx.x >> 4;
    int l0 = (blockIdx.x & 15) << 7;
    int lane = tid & 63;
    int wv = tid >> 6;
    int l15 = lane & 15, l4 = lane >> 4;

    if (tid < 64) {
        float sc = bg[tid] * rsqrtf(bv[tid] + 1e-5f);
        sscale[tid] = sc;
        sshift[tid] = bb[tid] - bm[tid] * sc;
    }
    __syncthreads();

    {
        int lcol = tid & 63;
        int ib = tid >> 6;
#pragma unroll
        for (int it = 0; it < 16; it++) {
            int i = ib + it * 4;
            float sc = sscale[i], sh = sshift[i];
            const float* ip = in + ((size_t)b * 64 + i) * TL;
#pragma unroll
            for (int jc = 0; jc < 3; jc++) {
                int ll = jc * 64 + lcol;
                if (ll < 138) {
                    int l = l0 - 5 + ll;
                    float v = 0.0f;
                    if (l >= 0 && l < TL) v = fmaxf(ip[l] * sc + sh, 0.0f);
                    unsigned short hb = f2bf(v);
                    float lo = v - bf2f(hb);
                    XTH[ll * XTS + i] = hb;
                    XTL[ll * XTS + i] = f2bf(lo);
                }
            }
        }
    }
    __syncthreads();

    f32x4 acc[2][4];
#pragma unroll
    for (int s = 0; s < 2; s++)
#pragma unroll
        for (int ot = 0; ot < 4; ot++) acc[s][ot] = (f32x4){0, 0, 0, 0};

    for (int k = 0; k < 11; k++) {
#pragma unroll
        for (int ic = 0; ic < 2; ic++) {
            bhalf8 ah[2], al[2];
#pragma unroll
            for (int s = 0; s < 2; s++) {
                int row = (wv * 2 + s) * 16 + l15 + k;
                int off = row * XTS + ic * 32 + l4 * 8;
                bhalf4 h0 = *(const bhalf4*)&XTH[off];
                bhalf4 h1v = *(const bhalf4*)&XTH[off + 4];
                bhalf4 lo0 = *(const bhalf4*)&XTL[off];
                bhalf4 lo1 = *(const bhalf4*)&XTL[off + 4];
                ah[s] = (bhalf8){h0[0], h0[1], h0[2], h0[3], h1v[0], h1v[1], h1v[2], h1v[3]};
                al[s] = (bhalf8){lo0[0], lo0[1], lo0[2], lo0[3], lo1[0], lo1[1], lo1[2], lo1[3]};
            }
#pragma unroll
            for (int ot = 0; ot < 4; ot++) {
                size_t woff = ((size_t)(k * 64 + ot * 16 + l15)) * 64 + ic * 32 + l4 * 8;
                bhalf8 bh = *(const bhalf8*)&wbh[woff];
                bhalf8 bl = *(const bhalf8*)&wbl[woff];
#pragma unroll
                for (int s = 0; s < 2; s++) {
                    acc[s][ot] = __builtin_amdgcn_mfma_f32_16x16x32_bf16(ah[s], bh, acc[s][ot], 0, 0, 0);
                    acc[s][ot] = __builtin_amdgcn_mfma_f32_16x16x32_bf16(al[s], bh, acc[s][ot], 0, 0, 0);
                    acc[s][ot] = __builtin_amdgcn_mfma_f32_16x16x32_bf16(ah[s], bl, acc[s][ot], 0, 0, 0);
                }
            }
        }
    }
    __syncthreads();

#pragma unroll
    for (int s = 0; s < 2; s++)
#pragma unroll
        for (int ot = 0; ot < 4; ot++)
#pragma unroll
            for (int r = 0; r < 4; r++)
                Yb[((wv * 2 + s) * 16 + l4 * 4 + r) * 66 + ot * 16 + l15] = acc[s][ot][r];
    __syncthreads();

    {
        int o = tid >> 2, ls0 = (tid & 3) * 32;
        float bsv = bias[o];
        float* op = out + ((size_t)b * 64 + o) * TL + l0 + ls0;
        if (accumulate) {
#pragma unroll
            for (int j = 0; j < 32; j++) op[j] += Yb[(ls0 + j) * 66 + o] + bsv;
        } else {
#pragma unroll
            for (int j = 0; j < 32; j++) op[j] = Yb[(ls0 + j) * 66 + o] + bsv;
        }
    }
}

// ---------------- transpose+cast: [NB][64][TL] f32 -> [TL][NB*64] bf16 ----------------
__global__ __launch_bounds__(256) void k_transpose(
    const float* __restrict__ x0, unsigned short* __restrict__ Xbf)
{
    __shared__ float t[64 * 65];
    int tid = threadIdx.x;
    int b = blockIdx.x >> 5;
    int t0 = (blockIdx.x & 31) << 6;
    for (int r = 0; r < 16; r++) {
        int idx = tid + 256 * r;
        int c = idx >> 6, tt = idx & 63;
        t[c * 65 + tt] = x0[((size_t)b * 64 + c) * TL + t0 + tt];
    }
    __syncthreads();
    for (int r = 0; r < 16; r++) {
        int idx = tid + 256 * r;
        int tt = idx >> 6, c = idx & 63;
        Xbf[((size_t)(t0 + tt)) * (NB * NH) + b * 64 + c] = f2bf(t[c * 65 + tt]);
    }
}

// ---------------- pipelined 10-layer LSTM: split-GEMM (Wx·x precomputed 1 step ahead) ----------------
// Critical chain per step: ds_read(h) -> 2-deep MFMA (init = xacc) -> nonlin -> h-write
// -> barrier. The 8 Wx MFMAs for step t+1 run in the shadow after the h-write.
// x: 4-slot LDS buffer (compile-time &3 indices), staged 2 steps ahead; prefetch
// distance 4 (load x(t+6) at step t) with exact vmcnt(9)/(3). All LDS row strides
// 72 ushorts (36 dwords = 4 mod 32 -> 2-way, free). Protocol constants unchanged.
__global__ __launch_bounds__(512) void k_lstm(
    const unsigned short* __restrict__ Xbf,
    const float* __restrict__ w_ih, const float* __restrict__ w_hh,
    const float* __restrict__ b_ih, const float* __restrict__ b_hh,
    unsigned short* __restrict__ ring, float* __restrict__ final_h, int* prog)
{
    int bid = blockIdx.x;             // 0..79; active: bid&7 < 4
    int grp = bid & 7;
    int layer = bid >> 3;
    if (grp >= 4 || layer >= NLAY) return;
    int b0 = grp * 16;
    int tid = threadIdx.x;
    int w = tid >> 6;                 // wave 0..7
    int lane = tid & 63;
    int l15 = lane & 15, l4 = lane >> 4;
    int w4 = w & 3;                   // u-range
    int rhalf = w >> 2;               // batch half within l4-quad
    int u = w4 * 16 + l15;            // this lane's u
    int self = layer * 4 + grp;
    const bool has_store = (layer < NLAY - 1);
    const bool use_ring = (layer > 0);
    int brow = tid >> 5;              // staging batch row 0..15
    int cc0 = (tid & 31) * 2;         // staging u pair base

    __shared__ __align__(16) unsigned short XB[4][16][72];  // x slots (stride 36 dw = 4 mod 32)
    __shared__ __align__(16) unsigned short HB[2][16][72];  // h double buffer

    const float LOG2E = 1.44269504f;

    // ---- weights: Bx (K=x), Bw (K=h), 4 gates x 2 kt each; pre-scaled ----
    bhalf8 Bx[4][2], Bw[4][2];
    float bv[4];
#pragma unroll
    for (int g = 0; g < 4; g++) {
        float wsc = (g == 2) ? 2.0f * LOG2E : LOG2E;
        int n = g * 64 + u;
        const float* rih = w_ih + ((size_t)layer * 256 + n) * 64;
        const float* rhh = w_hh + ((size_t)layer * 256 + n) * 64;
        bv[g] = (b_ih[layer * 256 + n] + b_hh[layer * 256 + n]) * wsc;
#pragma unroll
        for (int kt = 0; kt < 2; kt++) {
#pragma unroll
            for (int j = 0; j < 8; j++) {
                int k = kt * 32 + l4 * 8 + j;
                Bx[g][kt][j] = (short)f2bf(rih[k] * wsc);
                Bw[g][kt][j] = (short)f2bf(rhh[k] * wsc);
            }
        }
    }
    for (int idx = tid; idx < 2 * 16 * 64; idx += 512) {
        HB[idx >> 10][(idx >> 6) & 15][idx & 63] = 0;
    }
    float cst[2] = {0.f, 0.f};

    int* p_self = prog + self * 32;
    int* p_prev = prog + (self - 4) * 32;
    int* p_next = prog + (self + 4) * 32;
    int cached_prev = 0, cached_next = 0;

#define POLL_GE(ptr, tgt, cachev)                                                     \
    if (cachev < (tgt)) {                                                             \
        int v_; long g_ = 0;                                                          \
        while ((v_ = __hip_atomic_load(ptr, __ATOMIC_ACQUIRE,                         \
                        __HIP_MEMORY_SCOPE_AGENT)) < (tgt) && ++g_ < 1500000)         \
            __builtin_amdgcn_s_sleep(2);                                              \
        cachev = v_;                                                                  \
    }

    // ---- prologue: wait prev>=32; stage x(0),x(1); xacc(0); preload x(2..5) ----
    if (tid == 0 && layer > 0) { POLL_GE(p_prev, 32, cached_prev); }
    __syncthreads();
    {
        unsigned p0, p1;
        if (!use_ring) {
            const unsigned short* s0 = Xbf + (size_t)(b0 + brow) * 64 + cc0;
            asm volatile("global_load_dword %0, %1, off" : "=&v"(p0) : "v"(s0) : "memory");
            asm volatile("global_load_dword %0, %1, off" : "=&v"(p1) : "v"(s0 + NB * NH) : "memory");
        } else {
            const unsigned short* s0 = ring + ((size_t)(layer - 1) * RSTEP) * 4096 + (b0 + brow) * 64 + cc0;
            asm volatile("global_load_dword %0, %1, off sc0 sc1" : "=&v"(p0) : "v"(s0) : "memory");
            asm volatile("global_load_dword %0, %1, off sc0 sc1" : "=&v"(p1) : "v"(s0 + 4096) : "memory");
        }
        asm volatile("s_waitcnt vmcnt(0)" ::: "memory");
        __builtin_amdgcn_sched_barrier(0);
        *(unsigned*)&XB[0][brow][cc0] = p0;
        *(unsigned*)&XB[1][brow][cc0] = p1;
    }
    __syncthreads();
    f32x4 xac[4];
#pragma unroll
    for (int g = 0; g < 4; g++) xac[g] = (f32x4){bv[g], bv[g], bv[g], bv[g]};
#pragma unroll
    for (int kt = 0; kt < 2; kt++) {
        bhalf8 Ax = *(const bhalf8*)&XB[0][l15][kt * 32 + l4 * 8];
        xac[0] = __builtin_amdgcn_mfma_f32_16x16x32_bf16(Ax, Bx[0][kt], xac[0], 0, 0, 0);
        xac[1] = __builtin_amdgcn_mfma_f32_16x16x32_bf16(Ax, Bx[1][kt], xac[1], 0, 0, 0);
        xac[2] = __builtin_amdgcn_mfma_f32_16x16x32_bf16(Ax, Bx[2][kt], xac[2], 0, 0, 0);
        xac[3] = __builtin_amdgcn_mfma_f32_16x16x32_bf16(Ax, Bx[3][kt], xac[3], 0, 0, 0);
    }
    unsigned px[4];
#pragma unroll
    for (int pre = 2; pre <= 5; pre++) {
        if (!use_ring) {
            const unsigned short* sp = Xbf + ((size_t)pre * NB + b0 + brow) * 64 + cc0;
            asm volatile("global_load_dword %0, %1, off" : "=&v"(px[pre & 3]) : "v"(sp) : "memory");
        } else {
            const unsigned short* sp = ring + ((size_t)(layer - 1) * RSTEP + pre) * 4096 + (b0 + brow) * 64 + cc0;
            asm volatile("global_load_dword %0, %1, off sc0 sc1" : "=&v"(px[pre & 3]) : "v"(sp) : "memory");
        }
    }
    asm volatile("s_waitcnt vmcnt(0)" ::: "memory");
    __builtin_amdgcn_sched_barrier(0);
    __syncthreads();

    for (int t0 = 0; t0 < TL; t0 += 8) {
#pragma unroll
        for (int ts = 0; ts < 8; ++ts) {
            const int p = ts & 1, q = p ^ 1;
            const int t = t0 + ts;
            const int xs = (ts + 2) & 3;     // px slot + XB slot for x(t+2)
            const int xn = (ts + 1) & 3;     // XB slot holding x(t+1)

            // ---- hacc = xacc(t) + Wh·h(t-1): 2-deep chains (critical path) ----
            f32x4 hac0 = xac[0], hac1 = xac[1], hac2 = xac[2], hac3 = xac[3];
#pragma unroll
            for (int kt = 0; kt < 2; kt++) {
                bhalf8 Ah = *(const bhalf8*)&HB[p][l15][kt * 32 + l4 * 8];
                hac0 = __builtin_amdgcn_mfma_f32_16x16x32_bf16(Ah, Bw[0][kt], hac0, 0, 0, 0);
                hac1 = __builtin_amdgcn_mfma_f32_16x16x32_bf16(Ah, Bw[1][kt], hac1, 0, 0, 0);
                hac2 = __builtin_amdgcn_mfma_f32_16x16x32_bf16(Ah, Bw[2][kt], hac2, 0, 0, 0);
                hac3 = __builtin_amdgcn_mfma_f32_16x16x32_bf16(Ah, Bw[3][kt], hac3, 0, 0, 0);
            }

            // ---- nonlinearity (exp2-native) ----
            float hv[2];
#pragma unroll
            for (int rr = 0; rr < 2; rr++) {
                int r = rhalf * 2 + rr;
                float si = __builtin_amdgcn_rcpf(1.0f + exp2_neg(hac0[r]));
                float sf = __builtin_amdgcn_rcpf(1.0f + exp2_neg(hac1[r]));
                float tg = 1.0f - 2.0f * __builtin_amdgcn_rcpf(exp2_pos(hac2[r]) + 1.0f);
                float c = sf * cst[rr] + si * tg;
                cst[rr] = c;
                float tc = 1.0f - 2.0f * __builtin_amdgcn_rcpf(exp2_pos(c * (2.0f * LOG2E)) + 1.0f);
                float so = __builtin_amdgcn_rcpf(1.0f + exp2_neg(hac3[r]));
                hv[rr] = so * tc;
            }
            unsigned hpk;
            asm("v_cvt_pk_bf16_f32 %0, %1, %2" : "=v"(hpk) : "v"(hv[0]), "v"(hv[1]));
            unsigned hb0 = hpk & 0xffffu;
            unsigned hb1 = hpk >> 16;

            // ---- wait for x(t+2) (loaded 4 steps ago; 3 steps x [2 st + 1 ld] newer) ----
            if (has_store) { asm volatile("s_waitcnt vmcnt(9)" ::: "memory"); }
            else           { asm volatile("s_waitcnt vmcnt(3)" ::: "memory"); }
            __builtin_amdgcn_sched_barrier(0);

            // ---- stage x(t+2) into XB[xs] ----
            *(unsigned*)&XB[xs][brow][cc0] = px[xs];

            // ---- h into HB[q] + ring ----
            {
                int bb = l4 * 4 + rhalf * 2;
                HB[q][bb][u] = (unsigned short)hb0;
                HB[q][bb + 1][u] = (unsigned short)hb1;
                if (has_store) {
                    unsigned short* ap0 = ring + ((size_t)layer * RSTEP + (t & 63)) * 4096 + (b0 + bb) * 64 + u;
                    asm volatile("global_store_short %0, %1, off sc0 sc1" :: "v"(ap0), "v"(hb0) : "memory");
                    asm volatile("global_store_short %0, %1, off sc0 sc1" :: "v"(ap0 + 64), "v"(hb1) : "memory");
                } else if (t == TL - 1) {
                    final_h[(b0 + bb) * NH + u] = hv[0];
                    final_h[(b0 + bb + 1) * NH + u] = hv[1];
                }
            }

            // ---- prefetch x(t+6) into freed slot ----
            {
                int tt = t + 6; if (tt > TL - 1) tt = TL - 1;
                if (!use_ring) {
                    const unsigned short* sp = Xbf + ((size_t)tt * NB + b0 + brow) * 64 + cc0;
                    asm volatile("global_load_dword %0, %1, off" : "=&v"(px[xs]) : "v"(sp) : "memory");
                } else {
                    const unsigned short* sp = ring + ((size_t)(layer - 1) * RSTEP + (tt & 63)) * 4096 + (b0 + brow) * 64 + cc0;
                    asm volatile("global_load_dword %0, %1, off sc0 sc1" : "=&v"(px[xs]) : "v"(sp) : "memory");
                }
            }

            // ---- shadow: xacc(t+1) = bias + Wx·x(t+1) (off critical path) ----
#pragma unroll
            for (int g = 0; g < 4; g++) xac[g] = (f32x4){bv[g], bv[g], bv[g], bv[g]};
#pragma unroll
            for (int kt = 0; kt < 2; kt++) {
                bhalf8 Ax = *(const bhalf8*)&XB[xn][l15][kt * 32 + l4 * 8];
                xac[0] = __builtin_amdgcn_mfma_f32_16x16x32_bf16(Ax, Bx[0][kt], xac[0], 0, 0, 0);
                xac[1] = __builtin_amdgcn_mfma_f32_16x16x32_bf16(Ax, Bx[1][kt], xac[1], 0, 0, 0);
                xac[2] = __builtin_amdgcn_mfma_f32_16x16x32_bf16(Ax, Bx[2][kt], xac[2], 0, 0, 0);
                xac[3] = __builtin_amdgcn_mfma_f32_16x16x32_bf16(Ax, Bx[3][kt], xac[3], 0, 0, 0);
            }

            asm volatile("s_waitcnt lgkmcnt(0)" ::: "memory");
            __builtin_amdgcn_s_barrier();
            __builtin_amdgcn_sched_barrier(0);
        }

        // ---- superstep end: drain stores (vmcnt(1)), publish, slacked polls ----
        if (has_store) { asm volatile("s_waitcnt vmcnt(1)" ::: "memory"); }
        __builtin_amdgcn_s_barrier();
        __builtin_amdgcn_sched_barrier(0);
        if (tid == 0) {
            __hip_atomic_store(p_self, t0, __ATOMIC_RELEASE, __HIP_MEMORY_SCOPE_AGENT);
            int nt0 = t0 + 8;
            if (nt0 < TL) {
                if (use_ring) {
                    int tgt = nt0 + 16; if (tgt > TL) tgt = TL;
                    POLL_GE(p_prev, tgt, cached_prev);
                }
                if (has_store) {
                    int need = nt0 - 64;
                    if (need > 0) { POLL_GE(p_next, need, cached_next); }
                }
            }
        }
        __builtin_amdgcn_s_barrier();
        __builtin_amdgcn_sched_barrier(0);
    }

    // ---- epilogue ----
    asm volatile("s_waitcnt vmcnt(0)" ::: "memory");
    __builtin_amdgcn_s_barrier();
    if (tid == 0) {
        __hip_atomic_store(p_self, TL, __ATOMIC_RELEASE, __HIP_MEMORY_SCOPE_AGENT);
    }
#undef POLL_GE
}

// ---------------- head ----------------
__global__ void k_head(const float* __restrict__ fh, const float* __restrict__ ow,
                       const float* __restrict__ ob, float* __restrict__ out)
{
    int b = threadIdx.x;
    if (b >= NB) return;
    const float* h = fh + b * NH;
    float l0 = ob[0], l1 = ob[1];
    for (int uu = 0; uu < 64; uu++) { l0 += h[uu] * ow[uu * 2]; l1 += h[uu] * ow[uu * 2 + 1]; }
    float m = fmaxf(l0, l1);
    float s = expf(l0 - m) + expf(l1 - m);
    float ls = m + logf(s);
    out[b * 2] = l0 - ls;
    out[b * 2 + 1] = l1 - ls;
}

extern "C" void kernel_launch(void* const* d_in, const int* in_sizes, int n_in,
                              void* d_out, int out_size, void* d_ws, size_t ws_size,
                              hipStream_t stream) {
    const float* input = (const float*)d_in[0];
    const float* c1w = (const float*)d_in[2];
    const float* c1b = (const float*)d_in[3];
    const float* c2w = (const float*)d_in[4];
    const float* c2b = (const float*)d_in[5];
    const float* bn1g = (const float*)d_in[6];
    const float* bn1b = (const float*)d_in[7];
    const float* bn1m = (const float*)d_in[8];
    const float* bn1v = (const float*)d_in[9];
    const float* rw1 = (const float*)d_in[10];
    const float* rb1 = (const float*)d_in[11];
    const float* bn2g = (const float*)d_in[12];
    const float* bn2b = (const float*)d_in[13];
    const float* bn2m = (const float*)d_in[14];
    const float* bn2v = (const float*)d_in[15];
    const float* rw2 = (const float*)d_in[16];
    const float* rb2 = (const float*)d_in[17];
    const float* wih = (const float*)d_in[18];
    const float* whh = (const float*)d_in[19];
    const float* bih = (const float*)d_in[20];
    const float* bhh = (const float*)d_in[21];
    const float* outw = (const float*)d_in[22];
    const float* outb = (const float*)d_in[23];

    float* ws = (float*)d_ws;
    float*          x0buf = ws;                              // [NB][64][TL] f32
    float*          t1buf = x0buf + 8388608;                 // [NB][64][TL] f32
    unsigned short* Xbf   = (unsigned short*)(t1buf + 8388608);  // [TL][NB*64] bf16
    unsigned short* ringb = Xbf + 8388608;                   // [9][64][64b][64u] bf16
    float*          fhbuf = (float*)(ringb + 2359296);       // [NB][NH]
    int*            progb = (int*)(fhbuf + 4096);            // 40 flags x 32
    unsigned short* wbh1  = (unsigned short*)(progb + 40 * 32);   // [3][11][64][64]
    unsigned short* wbl1  = wbh1 + NRESU * 11 * 64 * 64;
    unsigned short* wbh2  = wbl1 + NRESU * 11 * 64 * 64;
    unsigned short* wbl2  = wbh2 + NRESU * 11 * 64 * 64;

    hipMemsetAsync(progb, 0, 40 * 32 * sizeof(int), stream);

    k_prepw_mfma<<<528, 256, 0, stream>>>(rw1, wbh1, wbl1);
    k_prepw_mfma<<<528, 256, 0, stream>>>(rw2, wbh2, wbl2);
    k_frontend<<<2048, 256, 0, stream>>>(input, c1w, c1b, c2w, c2b, x0buf);
    for (int uu = 0; uu < NRESU; uu++) {
        k_resconv_mfma<<<1024, 256, 0, stream>>>(x0buf, t1buf, wbh1 + uu * 45056, wbl1 + uu * 45056,
                                                 rb1 + uu * 64, bn1g + uu * 64, bn1b + uu * 64,
                                                 bn1m + uu * 64, bn1v + uu * 64, 0);
        k_resconv_mfma<<<1024, 256, 0, stream>>>(t1buf, x0buf, wbh2 + uu * 45056, wbl2 + uu * 45056,
                                                 rb2 + uu * 64, bn2g + uu * 64, bn2b + uu * 64,
                                                 bn2m + uu * 64, bn2v + uu * 64, 1);
    }
    k_transpose<<<2048, 256, 0, stream>>>(x0buf, Xbf);
    k_lstm<<<80, 512, 0, stream>>>(Xbf, wih, whh, bih, bhh, ringb, fhbuf, progb);
    k_head<<<1, 64, 0, stream>>>(fhbuf, outw, outb, (float*)d_out);
}